// Round 10
// baseline (179.578 us; speedup 1.0000x reference)
//
#include <hip/hip_runtime.h>
#include <stdint.h>

// Problem constants
#define B_  16
#define C_  256
#define T_  2048
#define K_  1024
#define TOTAL_ELEMS 8388608   // B*C*T

typedef short bf16x8 __attribute__((ext_vector_type(8)));
typedef float f32x4 __attribute__((ext_vector_type(4)));

// ---------- packed (dist, idx) ordering helpers ----------
__device__ __forceinline__ unsigned long long pack_key(float d, int idx) {
  unsigned u = __float_as_uint(d);
  u = (u & 0x80000000u) ? ~u : (u | 0x80000000u);   // monotone map f32 -> u32
  return ((unsigned long long)u << 32) | (unsigned)idx;
}
__device__ __forceinline__ float unpack_dist(unsigned long long key) {
  unsigned du = (unsigned)(key >> 32);
  unsigned bits = (du & 0x80000000u) ? (du ^ 0x80000000u) : ~du;
  return __uint_as_float(bits);
}

__device__ __forceinline__ unsigned short f2bf_rne(float f) {
  unsigned u = __float_as_uint(f);
  unsigned r = u + 0x7FFFu + ((u >> 16) & 1u);
  return (unsigned short)(r >> 16);
}

// ---------- prep: norms (0..11) + e0 -> fragment-linear bf16 ebt (12..267) + init (268..271) ----------
// ebt layout: element (code, c) with kk=c>>5, lg=(c>>3)&3, j=c&7 stored at
// shorts[ ((kk*1024 + code)*4 + lg)*8 + j ]  -> a wave's B-fragment load is 1024B contiguous.
__global__ __launch_bounds__(256) void prep_kernel(
    const float* __restrict__ e0, const float* __restrict__ e1,
    const float* __restrict__ e2, float* __restrict__ nrm,
    unsigned short* __restrict__ ebt, uint4* __restrict__ keysM_region,
    float* __restrict__ loss_accum, unsigned* __restrict__ counter) {
  int bid = blockIdx.x;
  int tid = threadIdx.x;
  if (bid < 12) {
    int i = bid * 256 + tid;             // 0..3071
    const float* e = (i < 1024) ? e0 : (i < 2048) ? e1 : e2;
    const float* p = e + (size_t)(i & 1023) * C_;
    float s = 0.0f;
    for (int c = 0; c < C_; c += 4) {
      float4 v = *(const float4*)(p + c);
      s = fmaf(v.x, v.x, s); s = fmaf(v.y, v.y, s);
      s = fmaf(v.z, v.z, s); s = fmaf(v.w, v.w, s);
    }
    nrm[i] = s;
  } else if (bid < 268) {
    // 256 blocks x 4 codes: transpose-convert e0 into fragment-linear ebt
    int code = (bid - 12) * 4 + (tid >> 6);
    int c = (tid & 63) * 4;
    float4 v = *(const float4*)(e0 + (size_t)code * C_ + c);
    unsigned lo = (unsigned)f2bf_rne(v.x) | ((unsigned)f2bf_rne(v.y) << 16);
    unsigned hi = (unsigned)f2bf_rne(v.z) | ((unsigned)f2bf_rne(v.w) << 16);
    int kk = c >> 5, lg = (c >> 3) & 3, j = c & 7;
    *(uint2*)(ebt + ((size_t)(kk * 1024 + code) * 4 + lg) * 8 + j) = make_uint2(lo, hi);
  } else {
    int i = (bid - 268) * 256 + tid;     // 0..1023: keysM (16384 B = 1024 uint4)
    keysM_region[i] = make_uint4(0xFFFFFFFFu, 0xFFFFFFFFu, 0xFFFFFFFFu, 0xFFFFFFFFu);
    if (bid == 268 && tid == 0) { *loss_accum = 0.0f; *counter = 0u; }
  }
}

// ---------- code-to-code maps as tiled f32 GEMM + argmin ----------
__global__ __launch_bounds__(256) void map_tile_kernel(
    const float* __restrict__ e0, const float* __restrict__ e1,
    const float* __restrict__ e2, const float* __restrict__ nrm,
    unsigned long long* __restrict__ keysM) {
  __shared__ float As[16][68];
  __shared__ float Bs[16][68];
  int bid = blockIdx.x;
  int m = bid >> 8;
  int tb = bid & 255;
  int ar0 = (tb >> 4) << 6;
  int br0 = (tb & 15) << 6;
  const float* Ap = m ? e1 : e0;
  const float* Bp = m ? e2 : e1;
  const float* nB = nrm + (m + 1) * 1024;

  int tid = threadIdx.x;
  int ty = tid >> 4, tx = tid & 15;
  int srow = tid >> 2;
  int skp  = (tid & 3) << 2;

  float acc[4][4];
#pragma unroll
  for (int i = 0; i < 4; i++)
#pragma unroll
    for (int j = 0; j < 4; j++) acc[i][j] = 0.0f;

  const float* gA = Ap + (size_t)(ar0 + srow) * C_ + skp;
  const float* gB = Bp + (size_t)(br0 + srow) * C_ + skp;

  for (int kk = 0; kk < C_; kk += 16) {
    float4 av = *(const float4*)(gA + kk);
    float4 bv = *(const float4*)(gB + kk);
    __syncthreads();
    As[skp + 0][srow] = av.x; As[skp + 1][srow] = av.y;
    As[skp + 2][srow] = av.z; As[skp + 3][srow] = av.w;
    Bs[skp + 0][srow] = bv.x; Bs[skp + 1][srow] = bv.y;
    Bs[skp + 2][srow] = bv.z; Bs[skp + 3][srow] = bv.w;
    __syncthreads();
#pragma unroll
    for (int k = 0; k < 16; k++) {
      float4 a4 = *(const float4*)&As[k][ty * 4];
      float4 b4 = *(const float4*)&Bs[k][tx * 4];
      float aa[4] = {a4.x, a4.y, a4.z, a4.w};
      float bb[4] = {b4.x, b4.y, b4.z, b4.w};
#pragma unroll
      for (int i = 0; i < 4; i++)
#pragma unroll
        for (int j = 0; j < 4; j++)
          acc[i][j] = fmaf(aa[i], bb[j], acc[i][j]);
    }
  }

  float nv[4];
#pragma unroll
  for (int j = 0; j < 4; j++) nv[j] = nB[br0 + tx * 4 + j];

#pragma unroll
  for (int i = 0; i < 4; i++) {
    unsigned long long best = 0xFFFFFFFFFFFFFFFFULL;
#pragma unroll
    for (int j = 0; j < 4; j++) {
      int code = br0 + tx * 4 + j;
      float s = nv[j] - 2.0f * acc[i][j];
      unsigned long long key = pack_key(s, code);
      if (key < best) best = key;
    }
#pragma unroll
    for (int off = 1; off < 16; off <<= 1) {
      unsigned long long o = __shfl_xor(best, off, 64);
      if (o < best) best = o;
    }
    if (tx == 0)
      atomicMin(&keysM[m * 1024 + ar0 + ty * 4 + i], best);
  }
}

// ---------- layer-0 fused: barrier-free MFMA distance GEMM + argmin + sum(x^2) ----------
// 256 blocks x 512 threads (8 waves). A (x-tile, 128 rows x 256 c) resident in LDS,
// k-major. B streamed to NAMED registers (bA0..3 / bB0..3, manual 2-step double
// buffer -> no runtime-indexed arrays, no scratch; rule #20). Main loop barrier-free.
// acc init = -||e||^2/2 so acc = -s/2; running (max,meta) in regs; keys written directly.
__global__ __launch_bounds__(512, 1) void l0_fused_kernel(
    const float* __restrict__ x, const unsigned short* __restrict__ ebt,
    const float* __restrict__ e0n, unsigned long long* __restrict__ keys,
    float* __restrict__ loss_accum) {
  extern __shared__ char Abuf[];                 // 64 KB dynamic
  __shared__ unsigned long long kred[128][4];
  __shared__ float red[8];

  int tid = threadIdx.x;                         // 0..511
  int l = tid & 63, w = tid >> 6;
  int lr = l & 15, lg = l >> 4;
  int wr = w >> 2, wc = w & 3;
  int row0 = blockIdx.x << 7;

  // ---- phase 1: x -> A_lds (transpose+cvt, k-major) + sum(x^2), non-temporal ----
  {
    int row = tid & 127;
    int cg  = tid >> 7;                          // 0..3
    int bb  = blockIdx.x >> 4;
    int t0  = (blockIdx.x & 15) << 7;
    const float* xb = x + (size_t)bb * (C_ * T_) + t0 + row;
    float sumsq = 0.0f;
#pragma unroll
    for (int i = 0; i < 8; i++) {
      int c0 = cg * 64 + i * 8;
      float v[8];
#pragma unroll
      for (int u = 0; u < 8; u++) {
        v[u] = __builtin_nontemporal_load(xb + (size_t)(c0 + u) * T_);
        sumsq = fmaf(v[u], v[u], sumsq);
      }
      unsigned pk[4];
#pragma unroll
      for (int j = 0; j < 4; j++)
        pk[j] = (unsigned)f2bf_rne(v[2 * j]) | ((unsigned)f2bf_rne(v[2 * j + 1]) << 16);
      int cc = c0 >> 3;
      *(uint4*)(Abuf + ((size_t)cc * 128 + row) * 16) =
          make_uint4(pk[0], pk[1], pk[2], pk[3]);
    }
    for (int off = 32; off > 0; off >>= 1) sumsq += __shfl_down(sumsq, off, 64);
    if (l == 0) red[w] = sumsq;
  }
  __syncthreads();                               // A ready; only barrier before epilogue
  if (tid == 0) {
    float s = 0.0f;
#pragma unroll
    for (int i = 0; i < 8; i++) s += red[i];
    atomicAdd(loss_accum, s);
  }

  // preload norms for all (p, ni)
  float nv[4][4];
#pragma unroll
  for (int p = 0; p < 4; p++)
#pragma unroll
    for (int ni = 0; ni < 4; ni++)
      nv[p][ni] = e0n[p * 256 + wc * 64 + ni * 16 + lr];

  // per-lane base into fragment-linear ebt
  const unsigned short* pB = ebt + ((size_t)(wc * 64 + lr) * 4 + lg) * 8;

  // load one B k-step (4 fragments) into the NAMED register set s##0..3
#define LOADB(s, p_, kk_) do {                                               \
    const unsigned short* q_ = pB + (size_t)(kk_) * 32768 + (p_) * 8192;     \
    s##0 = *(const bf16x8*)(q_);                                             \
    s##1 = *(const bf16x8*)(q_ + 512);                                       \
    s##2 = *(const bf16x8*)(q_ + 1024);                                      \
    s##3 = *(const bf16x8*)(q_ + 1536);                                      \
  } while (0)

  // one k-step: 4 named A-fragment loads + 16 MFMAs against named B set
#define DOKK(kk_, s) do {                                                    \
    const char* ab_ = Abuf + (size_t)((kk_) * 4 + lg) * 2048 +               \
                      (wr * 64 + lr) * 16;                                   \
    bf16x8 a0_ = *(const bf16x8*)(ab_);                                      \
    bf16x8 a1_ = *(const bf16x8*)(ab_ + 256);                                \
    bf16x8 a2_ = *(const bf16x8*)(ab_ + 512);                                \
    bf16x8 a3_ = *(const bf16x8*)(ab_ + 768);                                \
    acc[0][0] = __builtin_amdgcn_mfma_f32_16x16x32_bf16(a0_, s##0, acc[0][0], 0, 0, 0); \
    acc[1][0] = __builtin_amdgcn_mfma_f32_16x16x32_bf16(a1_, s##0, acc[1][0], 0, 0, 0); \
    acc[2][0] = __builtin_amdgcn_mfma_f32_16x16x32_bf16(a2_, s##0, acc[2][0], 0, 0, 0); \
    acc[3][0] = __builtin_amdgcn_mfma_f32_16x16x32_bf16(a3_, s##0, acc[3][0], 0, 0, 0); \
    acc[0][1] = __builtin_amdgcn_mfma_f32_16x16x32_bf16(a0_, s##1, acc[0][1], 0, 0, 0); \
    acc[1][1] = __builtin_amdgcn_mfma_f32_16x16x32_bf16(a1_, s##1, acc[1][1], 0, 0, 0); \
    acc[2][1] = __builtin_amdgcn_mfma_f32_16x16x32_bf16(a2_, s##1, acc[2][1], 0, 0, 0); \
    acc[3][1] = __builtin_amdgcn_mfma_f32_16x16x32_bf16(a3_, s##1, acc[3][1], 0, 0, 0); \
    acc[0][2] = __builtin_amdgcn_mfma_f32_16x16x32_bf16(a0_, s##2, acc[0][2], 0, 0, 0); \
    acc[1][2] = __builtin_amdgcn_mfma_f32_16x16x32_bf16(a1_, s##2, acc[1][2], 0, 0, 0); \
    acc[2][2] = __builtin_amdgcn_mfma_f32_16x16x32_bf16(a2_, s##2, acc[2][2], 0, 0, 0); \
    acc[3][2] = __builtin_amdgcn_mfma_f32_16x16x32_bf16(a3_, s##2, acc[3][2], 0, 0, 0); \
    acc[0][3] = __builtin_amdgcn_mfma_f32_16x16x32_bf16(a0_, s##3, acc[0][3], 0, 0, 0); \
    acc[1][3] = __builtin_amdgcn_mfma_f32_16x16x32_bf16(a1_, s##3, acc[1][3], 0, 0, 0); \
    acc[2][3] = __builtin_amdgcn_mfma_f32_16x16x32_bf16(a2_, s##3, acc[2][3], 0, 0, 0); \
    acc[3][3] = __builtin_amdgcn_mfma_f32_16x16x32_bf16(a3_, s##3, acc[3][3], 0, 0, 0); \
  } while (0)

  f32x4 acc[4][4];
  float bestv[4][4];
  int   bestm[4][4];
#pragma unroll
  for (int mi = 0; mi < 4; mi++)
#pragma unroll
    for (int r = 0; r < 4; r++) { bestv[mi][r] = -1e30f; bestm[mi][r] = 0; }

  bf16x8 bA0, bA1, bA2, bA3, bB0, bB1, bB2, bB3;
  LOADB(bA, 0, 0);

#pragma unroll
  for (int p = 0; p < 4; p++) {
#pragma unroll
    for (int ni = 0; ni < 4; ni++) {
      float iv = -0.5f * nv[p][ni];
      f32x4 ivv = {iv, iv, iv, iv};
#pragma unroll
      for (int mi = 0; mi < 4; mi++) acc[mi][ni] = ivv;
    }
#pragma unroll
    for (int kh = 0; kh < 4; kh++) {
      const int kk0 = 2 * kh, kk1 = 2 * kh + 1;
      LOADB(bB, p, kk1);
      DOKK(kk0, bA);
      if (kk1 < 7)    { LOADB(bA, p, kk1 + 1); }
      else if (p < 3) { LOADB(bA, p + 1, 0); }
      DOKK(kk1, bB);
    }
    // fold chunk into running best (strict > keeps lowest code on ties)
#pragma unroll
    for (int mi = 0; mi < 4; mi++)
#pragma unroll
      for (int r = 0; r < 4; r++)
#pragma unroll
        for (int ni = 0; ni < 4; ni++) {
          float v = acc[mi][ni][r];
          if (v > bestv[mi][r]) { bestv[mi][r] = v; bestm[mi][r] = p * 4 + ni; }
        }
  }
#undef LOADB
#undef DOKK

  // ---- epilogue: cross-lane reduce, direct keys write ----
#pragma unroll
  for (int mi = 0; mi < 4; mi++)
#pragma unroll
    for (int r = 0; r < 4; r++) {
      float sdist = -2.0f * bestv[mi][r];
      int m = bestm[mi][r];
      int code = ((m >> 2) << 8) | (wc << 6) | ((m & 3) << 4) | lr;
      unsigned long long key = pack_key(sdist, code);
#pragma unroll
      for (int off = 1; off < 16; off <<= 1) {
        unsigned long long o = __shfl_xor(key, off, 64);
        if (o < key) key = o;
      }
      if (lr == 0) kred[wr * 64 + mi * 16 + lg * 4 + r][wc] = key;
    }
  __syncthreads();
  if (tid < 128) {
    unsigned long long b0 = kred[tid][0], b1 = kred[tid][1];
    unsigned long long b2 = kred[tid][2], b3 = kred[tid][3];
    if (b1 < b0) b0 = b1;
    if (b3 < b2) b2 = b3;
    keys[row0 + tid] = b0 < b2 ? b0 : b2;
  }
}

// ---------- gather output + per-(b,t) loss terms + fused finalize ----------
__global__ __launch_bounds__(256) void finish_kernel(
    const float* __restrict__ emb2,
    const unsigned long long* __restrict__ keys,
    const unsigned long long* __restrict__ keysM,
    const float* __restrict__ nrm,
    float* __restrict__ out, float* __restrict__ loss_accum,
    unsigned* __restrict__ counter) {
  __shared__ int code2_l[64];
  __shared__ float rloss[64];
  int tid = threadIdx.x;
  int b  = blockIdx.x >> 5;
  int t0 = (blockIdx.x & 31) << 6;
  int tt = tid & 63, w = tid >> 6;

  if (w == 0) {
    unsigned long long key0 = keys[(size_t)b * T_ + t0 + tt];
    int idx0 = (int)(key0 & 0xFFFFFFFFULL);
    float s0 = unpack_dist(key0);
    unsigned long long k1 = keysM[idx0];
    int c1 = (int)(k1 & 0xFFFFFFFFULL);
    unsigned long long k2 = keysM[1024 + c1];
    code2_l[tt] = (int)(k2 & 0xFFFFFFFFULL);
    rloss[tt] = s0 + nrm[idx0] + unpack_dist(k1) + nrm[1024 + c1] + unpack_dist(k2);
  }
  __syncthreads();

  float* ob = out + ((size_t)b << 19);
  int code2 = code2_l[tt];
  const float* e2row = emb2 + (size_t)code2 * C_;
  for (int c4 = w * 64; c4 < w * 64 + 64; c4 += 4) {
    float4 ev = *(const float4*)(e2row + c4);
    float evv[4] = {ev.x, ev.y, ev.z, ev.w};
#pragma unroll
    for (int u = 0; u < 4; u++)
      __builtin_nontemporal_store(evv[u], ob + (size_t)(c4 + u) * T_ + t0 + tt);
  }
  if (w == 0) {
    float tot = rloss[tt];
    for (int off = 32; off > 0; off >>= 1)
      tot += __shfl_down(tot, off, 64);
    if (tt == 0) atomicAdd(loss_accum, tot);
  }
  if (tid == 0) {
    __threadfence();
    unsigned old = atomicAdd(counter, 1u);
    if (old == 511u) {
      float L = atomicAdd(loss_accum, 0.0f);   // device-scope read
      out[TOTAL_ELEMS] = 2.0f * L / 8388608.0f;
    }
  }
}

extern "C" void kernel_launch(void* const* d_in, const int* in_sizes, int n_in,
                              void* d_out, int out_size, void* d_ws, size_t ws_size,
                              hipStream_t stream) {
  const float* x  = (const float*)d_in[0];
  const float* e0 = (const float*)d_in[1];
  const float* e1 = (const float*)d_in[2];
  const float* e2 = (const float*)d_in[3];
  float* out = (float*)d_out;
  char* ws = (char*)d_ws;

  unsigned long long* keys  = (unsigned long long*)ws;            // 262144 B
  unsigned long long* keysM = (unsigned long long*)(ws + 262144); // 16384 B
  float* nrm  = (float*)(ws + 278528);                            // 12288 B
  float* loss_accum = (float*)(ws + 290816);                      // 4 B
  unsigned* counter = (unsigned*)(ws + 290820);                   // 4 B
  unsigned short* ebt = (unsigned short*)(ws + 294912);           // 524288 B (frag-linear e0)

  prep_kernel<<<272, 256, 0, stream>>>(e0, e1, e2, nrm, ebt, (uint4*)keysM,
                                       loss_accum, counter);
  l0_fused_kernel<<<256, 512, 65536, stream>>>(x, ebt, nrm, keys, loss_accum);
  map_tile_kernel<<<512, 256, 0, stream>>>(e0, e1, e2, nrm, keysM);
  finish_kernel<<<512, 256, 0, stream>>>(e2, keys, keysM, nrm, out, loss_accum, counter);
}

// Round 11
// 109.410 us; speedup vs baseline: 1.6413x; 1.6413x over previous
//
#include <hip/hip_runtime.h>
#include <stdint.h>

// Problem constants
#define B_  16
#define C_  256
#define T_  2048
#define K_  1024
#define TOTAL_ELEMS 8388608   // B*C*T

typedef short bf16x8 __attribute__((ext_vector_type(8)));
typedef float f32x4 __attribute__((ext_vector_type(4)));

// ---------- packed (dist, idx) ordering helpers ----------
__device__ __forceinline__ unsigned long long pack_key(float d, int idx) {
  unsigned u = __float_as_uint(d);
  u = (u & 0x80000000u) ? ~u : (u | 0x80000000u);   // monotone map f32 -> u32
  return ((unsigned long long)u << 32) | (unsigned)idx;
}
__device__ __forceinline__ float unpack_dist(unsigned long long key) {
  unsigned du = (unsigned)(key >> 32);
  unsigned bits = (du & 0x80000000u) ? (du ^ 0x80000000u) : ~du;
  return __uint_as_float(bits);
}

__device__ __forceinline__ unsigned short f2bf_rne(float f) {
  unsigned u = __float_as_uint(f);
  unsigned r = u + 0x7FFFu + ((u >> 16) & 1u);
  return (unsigned short)(r >> 16);
}

// ---------- prep: norms (0..11) + e0 -> fragment-linear bf16 ebt (12..267) + init (268..271) ----------
// ebt layout: element (code, c) with kk=c>>5, lg=(c>>3)&3, j=c&7 stored at
// shorts[ ((kk*1024 + code)*4 + lg)*8 + j ]  -> a wave's B-fragment load is 1024B contiguous.
__global__ __launch_bounds__(256) void prep_kernel(
    const float* __restrict__ e0, const float* __restrict__ e1,
    const float* __restrict__ e2, float* __restrict__ nrm,
    unsigned short* __restrict__ ebt, uint4* __restrict__ keysM_region,
    float* __restrict__ loss_accum, unsigned* __restrict__ counter) {
  int bid = blockIdx.x;
  int tid = threadIdx.x;
  if (bid < 12) {
    int i = bid * 256 + tid;             // 0..3071
    const float* e = (i < 1024) ? e0 : (i < 2048) ? e1 : e2;
    const float* p = e + (size_t)(i & 1023) * C_;
    float s = 0.0f;
    for (int c = 0; c < C_; c += 4) {
      float4 v = *(const float4*)(p + c);
      s = fmaf(v.x, v.x, s); s = fmaf(v.y, v.y, s);
      s = fmaf(v.z, v.z, s); s = fmaf(v.w, v.w, s);
    }
    nrm[i] = s;
  } else if (bid < 268) {
    // 256 blocks x 4 codes: transpose-convert e0 into fragment-linear ebt
    int code = (bid - 12) * 4 + (tid >> 6);
    int c = (tid & 63) * 4;
    float4 v = *(const float4*)(e0 + (size_t)code * C_ + c);
    unsigned lo = (unsigned)f2bf_rne(v.x) | ((unsigned)f2bf_rne(v.y) << 16);
    unsigned hi = (unsigned)f2bf_rne(v.z) | ((unsigned)f2bf_rne(v.w) << 16);
    int kk = c >> 5, lg = (c >> 3) & 3, j = c & 7;
    *(uint2*)(ebt + ((size_t)(kk * 1024 + code) * 4 + lg) * 8 + j) = make_uint2(lo, hi);
  } else {
    int i = (bid - 268) * 256 + tid;     // 0..1023: keysM (16384 B = 1024 uint4)
    keysM_region[i] = make_uint4(0xFFFFFFFFu, 0xFFFFFFFFu, 0xFFFFFFFFu, 0xFFFFFFFFu);
    if (bid == 268 && tid == 0) { *loss_accum = 0.0f; *counter = 0u; }
  }
}

// ---------- code-to-code maps as tiled f32 GEMM + argmin ----------
__global__ __launch_bounds__(256) void map_tile_kernel(
    const float* __restrict__ e0, const float* __restrict__ e1,
    const float* __restrict__ e2, const float* __restrict__ nrm,
    unsigned long long* __restrict__ keysM) {
  __shared__ float As[16][68];
  __shared__ float Bs[16][68];
  int bid = blockIdx.x;
  int m = bid >> 8;
  int tb = bid & 255;
  int ar0 = (tb >> 4) << 6;
  int br0 = (tb & 15) << 6;
  const float* Ap = m ? e1 : e0;
  const float* Bp = m ? e2 : e1;
  const float* nB = nrm + (m + 1) * 1024;

  int tid = threadIdx.x;
  int ty = tid >> 4, tx = tid & 15;
  int srow = tid >> 2;
  int skp  = (tid & 3) << 2;

  float acc[4][4];
#pragma unroll
  for (int i = 0; i < 4; i++)
#pragma unroll
    for (int j = 0; j < 4; j++) acc[i][j] = 0.0f;

  const float* gA = Ap + (size_t)(ar0 + srow) * C_ + skp;
  const float* gB = Bp + (size_t)(br0 + srow) * C_ + skp;

  for (int kk = 0; kk < C_; kk += 16) {
    float4 av = *(const float4*)(gA + kk);
    float4 bv = *(const float4*)(gB + kk);
    __syncthreads();
    As[skp + 0][srow] = av.x; As[skp + 1][srow] = av.y;
    As[skp + 2][srow] = av.z; As[skp + 3][srow] = av.w;
    Bs[skp + 0][srow] = bv.x; Bs[skp + 1][srow] = bv.y;
    Bs[skp + 2][srow] = bv.z; Bs[skp + 3][srow] = bv.w;
    __syncthreads();
#pragma unroll
    for (int k = 0; k < 16; k++) {
      float4 a4 = *(const float4*)&As[k][ty * 4];
      float4 b4 = *(const float4*)&Bs[k][tx * 4];
      float aa[4] = {a4.x, a4.y, a4.z, a4.w};
      float bb[4] = {b4.x, b4.y, b4.z, b4.w};
#pragma unroll
      for (int i = 0; i < 4; i++)
#pragma unroll
        for (int j = 0; j < 4; j++)
          acc[i][j] = fmaf(aa[i], bb[j], acc[i][j]);
    }
  }

  float nv[4];
#pragma unroll
  for (int j = 0; j < 4; j++) nv[j] = nB[br0 + tx * 4 + j];

#pragma unroll
  for (int i = 0; i < 4; i++) {
    unsigned long long best = 0xFFFFFFFFFFFFFFFFULL;
#pragma unroll
    for (int j = 0; j < 4; j++) {
      int code = br0 + tx * 4 + j;
      float s = nv[j] - 2.0f * acc[i][j];
      unsigned long long key = pack_key(s, code);
      if (key < best) best = key;
    }
#pragma unroll
    for (int off = 1; off < 16; off <<= 1) {
      unsigned long long o = __shfl_xor(best, off, 64);
      if (o < best) best = o;
    }
    if (tx == 0)
      atomicMin(&keysM[m * 1024 + ar0 + ty * 4 + i], best);
  }
}

// ---------- layer-0 fused: MFMA distance GEMM + argmin + sum(x^2), low-pressure ----------
// 512 blocks x 256 threads (4 waves: wr,wc in {0,1}; 2 blocks/CU). Each block: 64 rows,
// all 1024 codes. A (64 rows x 256 c bf16 = 32 KB) resident in LDS, k-major slots
// (cc*64+row)*16 -> conflict-free b128 frag reads. B streamed to NAMED regs (bA/bB
// 2-step double buffer) from fragment-linear ebt, 1KB/wave contiguous, L2-resident.
// Per-thread regs ~100 (acc 2x4 frags=32, B 32, best 16) -> no spill at any cap.
// acc init = -||e||^2/2 so acc = -s/2; keys written directly (no atomics/init).
__global__ __launch_bounds__(256, 2) void l0_fused_kernel(
    const float* __restrict__ x, const unsigned short* __restrict__ ebt,
    const float* __restrict__ e0n, unsigned long long* __restrict__ keys,
    float* __restrict__ loss_accum) {
  __shared__ __align__(16) char Abuf[32768];
  __shared__ unsigned long long kred[64][2];
  __shared__ float red[4];

  int tid = threadIdx.x;                         // 0..255
  int l = tid & 63, w = tid >> 6;                // 4 waves
  int lr = l & 15, lg = l >> 4;
  int wr = w >> 1, wc = w & 1;
  int row0 = blockIdx.x << 6;

  // ---- phase 1: x -> A_lds (transpose+cvt, k-major) + sum(x^2), non-temporal ----
  {
    int bb = blockIdx.x >> 5;
    int t0 = (blockIdx.x & 31) << 6;
    const float* xb = x + (size_t)bb * (C_ * T_) + t0 + l;
    float sumsq = 0.0f;
#pragma unroll
    for (int i = 0; i < 8; i++) {
      int c0 = w * 64 + i * 8;
      float v[8];
#pragma unroll
      for (int u = 0; u < 8; u++) {
        v[u] = __builtin_nontemporal_load(xb + (size_t)(c0 + u) * T_);
        sumsq = fmaf(v[u], v[u], sumsq);
      }
      unsigned pk[4];
#pragma unroll
      for (int j = 0; j < 4; j++)
        pk[j] = (unsigned)f2bf_rne(v[2 * j]) | ((unsigned)f2bf_rne(v[2 * j + 1]) << 16);
      int cc = w * 8 + i;                        // k-major slot plane
      *(uint4*)(Abuf + ((size_t)cc * 64 + l) * 16) =
          make_uint4(pk[0], pk[1], pk[2], pk[3]);
    }
    for (int off = 32; off > 0; off >>= 1) sumsq += __shfl_down(sumsq, off, 64);
    if (l == 0) red[w] = sumsq;
  }
  __syncthreads();                               // A ready
  if (tid == 0)
    atomicAdd(loss_accum, red[0] + red[1] + red[2] + red[3]);

  // per-lane base into fragment-linear ebt (code base wc*64+lr, k-slot lg)
  const unsigned short* pB = ebt + (size_t)(wc * 64 + lr) * 32 + lg * 8;

#define LOADB(s, p_, kk_) do {                                               \
    const unsigned short* q_ = pB + (size_t)(kk_) * 32768 + (size_t)(p_) * 4096; \
    s##0 = *(const bf16x8*)(q_);                                             \
    s##1 = *(const bf16x8*)(q_ + 512);                                       \
    s##2 = *(const bf16x8*)(q_ + 1024);                                      \
    s##3 = *(const bf16x8*)(q_ + 1536);                                      \
  } while (0)

#define DOKK(kk_, s) do {                                                    \
    const char* ab_ = Abuf + (size_t)((kk_) * 4 + lg) * 1024 +               \
                      (wr * 32 + lr) * 16;                                   \
    bf16x8 a0_ = *(const bf16x8*)(ab_);                                      \
    bf16x8 a1_ = *(const bf16x8*)(ab_ + 256);                                \
    acc[0][0] = __builtin_amdgcn_mfma_f32_16x16x32_bf16(a0_, s##0, acc[0][0], 0, 0, 0); \
    acc[1][0] = __builtin_amdgcn_mfma_f32_16x16x32_bf16(a1_, s##0, acc[1][0], 0, 0, 0); \
    acc[0][1] = __builtin_amdgcn_mfma_f32_16x16x32_bf16(a0_, s##1, acc[0][1], 0, 0, 0); \
    acc[1][1] = __builtin_amdgcn_mfma_f32_16x16x32_bf16(a1_, s##1, acc[1][1], 0, 0, 0); \
    acc[0][2] = __builtin_amdgcn_mfma_f32_16x16x32_bf16(a0_, s##2, acc[0][2], 0, 0, 0); \
    acc[1][2] = __builtin_amdgcn_mfma_f32_16x16x32_bf16(a1_, s##2, acc[1][2], 0, 0, 0); \
    acc[0][3] = __builtin_amdgcn_mfma_f32_16x16x32_bf16(a0_, s##3, acc[0][3], 0, 0, 0); \
    acc[1][3] = __builtin_amdgcn_mfma_f32_16x16x32_bf16(a1_, s##3, acc[1][3], 0, 0, 0); \
  } while (0)

  f32x4 acc[2][4];
  float bestv[2][4];
  int   bestm[2][4];
#pragma unroll
  for (int mi = 0; mi < 2; mi++)
#pragma unroll
    for (int r = 0; r < 4; r++) { bestv[mi][r] = -1e30f; bestm[mi][r] = 0; }

  bf16x8 bA0, bA1, bA2, bA3, bB0, bB1, bB2, bB3;
  LOADB(bA, 0, 0);

  for (int p = 0; p < 8; p++) {                  // 8 chunks of 128 codes
#pragma unroll
    for (int ni = 0; ni < 4; ni++) {
      float iv = -0.5f * e0n[p * 128 + wc * 64 + ni * 16 + lr];
      f32x4 ivv = {iv, iv, iv, iv};
      acc[0][ni] = ivv;
      acc[1][ni] = ivv;
    }
#pragma unroll
    for (int kh = 0; kh < 4; kh++) {
      const int kk0 = 2 * kh, kk1 = 2 * kh + 1;
      LOADB(bB, p, kk1);
      DOKK(kk0, bA);
      if (kk1 < 7)    { LOADB(bA, p, kk1 + 1); }
      else if (p < 7) { LOADB(bA, p + 1, 0); }
      DOKK(kk1, bB);
    }
    // fold chunk into running best (strict > keeps lowest code on ties)
#pragma unroll
    for (int mi = 0; mi < 2; mi++)
#pragma unroll
      for (int r = 0; r < 4; r++)
#pragma unroll
        for (int ni = 0; ni < 4; ni++) {
          float v = acc[mi][ni][r];
          if (v > bestv[mi][r]) { bestv[mi][r] = v; bestm[mi][r] = p * 4 + ni; }
        }
  }
#undef LOADB
#undef DOKK

  // ---- epilogue: cross-lane reduce, direct keys write ----
#pragma unroll
  for (int mi = 0; mi < 2; mi++)
#pragma unroll
    for (int r = 0; r < 4; r++) {
      float sdist = -2.0f * bestv[mi][r];
      int m = bestm[mi][r];
      int code = ((m >> 2) << 7) | (wc << 6) | ((m & 3) << 4) | lr;
      unsigned long long key = pack_key(sdist, code);
#pragma unroll
      for (int off = 1; off < 16; off <<= 1) {
        unsigned long long o = __shfl_xor(key, off, 64);
        if (o < key) key = o;
      }
      if (lr == 0) kred[wr * 32 + mi * 16 + lg * 4 + r][wc] = key;
    }
  __syncthreads();
  if (tid < 64) {
    unsigned long long b0 = kred[tid][0], b1 = kred[tid][1];
    keys[row0 + tid] = b0 < b1 ? b0 : b1;
  }
}

// ---------- gather output + per-(b,t) loss terms + fused finalize ----------
__global__ __launch_bounds__(256) void finish_kernel(
    const float* __restrict__ emb2,
    const unsigned long long* __restrict__ keys,
    const unsigned long long* __restrict__ keysM,
    const float* __restrict__ nrm,
    float* __restrict__ out, float* __restrict__ loss_accum,
    unsigned* __restrict__ counter) {
  __shared__ int code2_l[64];
  __shared__ float rloss[64];
  int tid = threadIdx.x;
  int b  = blockIdx.x >> 5;
  int t0 = (blockIdx.x & 31) << 6;
  int tt = tid & 63, w = tid >> 6;

  if (w == 0) {
    unsigned long long key0 = keys[(size_t)b * T_ + t0 + tt];
    int idx0 = (int)(key0 & 0xFFFFFFFFULL);
    float s0 = unpack_dist(key0);
    unsigned long long k1 = keysM[idx0];
    int c1 = (int)(k1 & 0xFFFFFFFFULL);
    unsigned long long k2 = keysM[1024 + c1];
    code2_l[tt] = (int)(k2 & 0xFFFFFFFFULL);
    rloss[tt] = s0 + nrm[idx0] + unpack_dist(k1) + nrm[1024 + c1] + unpack_dist(k2);
  }
  __syncthreads();

  float* ob = out + ((size_t)b << 19);
  int code2 = code2_l[tt];
  const float* e2row = emb2 + (size_t)code2 * C_;
  for (int c4 = w * 64; c4 < w * 64 + 64; c4 += 4) {
    float4 ev = *(const float4*)(e2row + c4);
    float evv[4] = {ev.x, ev.y, ev.z, ev.w};
#pragma unroll
    for (int u = 0; u < 4; u++)
      __builtin_nontemporal_store(evv[u], ob + (size_t)(c4 + u) * T_ + t0 + tt);
  }
  if (w == 0) {
    float tot = rloss[tt];
    for (int off = 32; off > 0; off >>= 1)
      tot += __shfl_down(tot, off, 64);
    if (tt == 0) atomicAdd(loss_accum, tot);
  }
  if (tid == 0) {
    __threadfence();
    unsigned old = atomicAdd(counter, 1u);
    if (old == 511u) {
      float L = atomicAdd(loss_accum, 0.0f);   // device-scope read
      out[TOTAL_ELEMS] = 2.0f * L / 8388608.0f;
    }
  }
}

extern "C" void kernel_launch(void* const* d_in, const int* in_sizes, int n_in,
                              void* d_out, int out_size, void* d_ws, size_t ws_size,
                              hipStream_t stream) {
  const float* x  = (const float*)d_in[0];
  const float* e0 = (const float*)d_in[1];
  const float* e1 = (const float*)d_in[2];
  const float* e2 = (const float*)d_in[3];
  float* out = (float*)d_out;
  char* ws = (char*)d_ws;

  unsigned long long* keys  = (unsigned long long*)ws;            // 262144 B
  unsigned long long* keysM = (unsigned long long*)(ws + 262144); // 16384 B
  float* nrm  = (float*)(ws + 278528);                            // 12288 B
  float* loss_accum = (float*)(ws + 290816);                      // 4 B
  unsigned* counter = (unsigned*)(ws + 290820);                   // 4 B
  unsigned short* ebt = (unsigned short*)(ws + 294912);           // 524288 B (frag-linear e0)

  prep_kernel<<<272, 256, 0, stream>>>(e0, e1, e2, nrm, ebt, (uint4*)keysM,
                                       loss_accum, counter);
  l0_fused_kernel<<<512, 256, 0, stream>>>(x, ebt, nrm, keys, loss_accum);
  map_tile_kernel<<<512, 256, 0, stream>>>(e0, e1, e2, nrm, keysM);
  finish_kernel<<<512, 256, 0, stream>>>(e2, keys, keysM, nrm, out, loss_accum, counter);
}